// Round 3
// baseline (264.205 us; speedup 1.0000x reference)
//
#include <hip/hip_runtime.h>

#define NPTS 40000
#define BDIM 4
#define FIN  128
#define CCH  128
#define DVOX 16
#define SVOL 4096   // 16*16*16
#define OROW 259    // FIN + CCH + 3

typedef float fx4 __attribute__((ext_vector_type(4)));   // nontemporal-compatible

// ---------------------------------------------------------------------------
// Kernel T: transpose conv [B,128,4096] -> convt [B,4096,128] so that the
// per-corner gather reads 128 consecutive channels (coalesced).
// ---------------------------------------------------------------------------
__global__ __launch_bounds__(256) void transpose_conv(const float* __restrict__ conv,
                                                      float* __restrict__ convt) {
    __shared__ float tile[128][65];           // +1 pad: conflict-free both phases
    const int b  = blockIdx.y;
    const int s0 = blockIdx.x * 64;
    const int t  = threadIdx.x;

    const float* src = conv + (size_t)b * 128 * SVOL;
    #pragma unroll
    for (int i = 0; i < 32; ++i) {
        int e  = t + 256 * i;                 // 8192 elements
        int c  = e >> 6;                      // 0..127
        int sl = e & 63;                      // coalesced along s
        tile[c][sl] = src[(size_t)c * SVOL + s0 + sl];
    }
    __syncthreads();
    float* dst = convt + ((size_t)b * SVOL + s0) * 128;
    #pragma unroll
    for (int i = 0; i < 32; ++i) {
        int e  = t + 256 * i;
        int sl = e >> 7;                      // 0..63
        int c  = e & 127;                     // coalesced along c
        dst[(size_t)sl * 128 + c] = tile[c][sl];
    }
}

// ---------------------------------------------------------------------------
// Kernel M: fused projection + trilinear sample + concat write.
// Block = 256 threads (4 waves), 64 points. Grid = (625, B).
// TR: vol is the transposed [B,4096,128] layout (fast path).
// ---------------------------------------------------------------------------
template <bool TR>
__global__ __launch_bounds__(256) void igsc_main(const float* __restrict__ x,
                                                 const float* __restrict__ vol,
                                                 const float* __restrict__ Wm,
                                                 float* __restrict__ out,
                                                 float* __restrict__ pos_out) {
    __shared__ float xs[64 * 132];            // x tile, padded rows (132)
    __shared__ float Ws[FIN * 3];
    __shared__ float wgt[64][8];
    __shared__ int   idx8[64][8];
    __shared__ float ps[64][3];

    const int t  = threadIdx.x;
    const int b  = blockIdx.y;
    const int p0 = blockIdx.x * 64;

    // ---- stage x tile (coalesced float4, nontemporal: stream-once) ----
    const float* xsrc = x + ((size_t)b * NPTS + p0) * FIN;
    #pragma unroll
    for (int i = 0; i < 8; ++i) {
        int e  = t + 256 * i;                 // 2048 float4
        int p  = e >> 5;                      // 32 float4 per 128-float row
        int f4 = e & 31;
        fx4 v = __builtin_nontemporal_load(&((const fx4*)xsrc)[e]);
        ((fx4*)&xs[p * 132])[f4] = v;
    }
    if (t < 96) ((fx4*)Ws)[t] = ((const fx4*)Wm)[t];   // 384 floats
    __syncthreads();

    // ---- positions: 4 threads per point, interleaved features ----
    {
        const int p = t >> 2, q = t & 3;
        const float* xr = &xs[p * 132];
        float a0 = 0.f, a1 = 0.f, a2 = 0.f;
        #pragma unroll
        for (int i = 0; i < 32; ++i) {
            int   f  = q + 4 * i;
            float xv = xr[f];
            a0 = fmaf(xv, Ws[f * 3 + 0], a0);
            a1 = fmaf(xv, Ws[f * 3 + 1], a1);
            a2 = fmaf(xv, Ws[f * 3 + 2], a2);
        }
        a0 += __shfl_xor(a0, 1); a0 += __shfl_xor(a0, 2);
        a1 += __shfl_xor(a1, 1); a1 += __shfl_xor(a1, 2);
        a2 += __shfl_xor(a2, 1); a2 += __shfl_xor(a2, 2);

        if (q == 0) {
            ps[p][0] = a0; ps[p][1] = a1; ps[p][2] = a2;
            // replicate reference rounding: g = 2p-1; i = (g+1)*0.5*(dim-1)
            float gx = 2.f * a0 - 1.f, gy = 2.f * a1 - 1.f, gz = 2.f * a2 - 1.f;
            float ix = (gx + 1.f) * 0.5f * 15.f;
            float iy = (gy + 1.f) * 0.5f * 15.f;
            float iz = (gz + 1.f) * 0.5f * 15.f;
            float x0f = floorf(ix), y0f = floorf(iy), z0f = floorf(iz);
            float fx = ix - x0f, fy = iy - y0f, fz = iz - z0f;
            int x0 = (int)x0f, y0 = (int)y0f, z0 = (int)z0f;
            #pragma unroll
            for (int k = 0; k < 8; ++k) {       // corner order matches reference
                int dx = k & 1, dy = (k >> 1) & 1, dz = k >> 2;
                int xc = x0 + dx, yc = y0 + dy, zc = z0 + dz;
                bool valid = (xc >= 0) & (xc < DVOX) & (yc >= 0) & (yc < DVOX) &
                             (zc >= 0) & (zc < DVOX);
                int xcc = min(max(xc, 0), DVOX - 1);
                int ycc = min(max(yc, 0), DVOX - 1);
                int zcc = min(max(zc, 0), DVOX - 1);
                float wx = dx ? fx : 1.f - fx;
                float wy = dy ? fy : 1.f - fy;
                float wz = dz ? fz : 1.f - fz;
                wgt[p][k]  = valid ? wx * wy * wz : 0.f;
                idx8[p][k] = (zcc * DVOX + ycc) * DVOX + xcc;
            }
        }
    }
    __syncthreads();

    // ---- sampling + output write: each wave handles 16 points ----
    const int wave = t >> 6, lane = t & 63;
    const float* volb = vol + (size_t)b * SVOL * CCH;   // same total either layout
    for (int pp = wave * 16; pp < wave * 16 + 16; ++pp) {
        float acc0 = 0.f, acc1 = 0.f;   // channels 2*lane, 2*lane+1 (TR path)
        #pragma unroll
        for (int k = 0; k < 8; ++k) {
            float w = wgt[pp][k];               // wave-uniform (LDS broadcast)
            if (w != 0.f) {                     // skip OOB / zero-weight corners
                int idx = idx8[pp][k];
                if (TR) {
                    const float2 v = ((const float2*)(volb + (size_t)idx * CCH))[lane];
                    acc0 = fmaf(w, v.x, acc0);
                    acc1 = fmaf(w, v.y, acc1);
                } else {
                    acc0 = fmaf(w, volb[(size_t)(2 * lane) * SVOL + idx], acc0);
                    acc1 = fmaf(w, volb[(size_t)(2 * lane + 1) * SVOL + idx], acc1);
                }
            }
        }
        size_t row  = (size_t)b * NPTS + p0 + pp;
        float* orow = out + row * OROW;
        __builtin_nontemporal_store(xs[pp * 132 + lane],      &orow[lane]);
        __builtin_nontemporal_store(xs[pp * 132 + 64 + lane], &orow[64 + lane]);
        // skip channels: lane holds channels 2*lane, 2*lane+1
        __builtin_nontemporal_store(acc0, &orow[128 + 2 * lane]);
        __builtin_nontemporal_store(acc1, &orow[128 + 2 * lane + 1]);
        if (lane < 3) {
            float pv = ps[pp][lane];
            __builtin_nontemporal_store(pv, &orow[256 + lane]);      // positions
            __builtin_nontemporal_store(pv, &pos_out[row * 3 + lane]); // 2nd output
        }
    }
}

// ---------------------------------------------------------------------------
extern "C" void kernel_launch(void* const* d_in, const int* in_sizes, int n_in,
                              void* d_out, int out_size, void* d_ws, size_t ws_size,
                              hipStream_t stream) {
    const float* x    = (const float*)d_in[0];
    // d_in[1] = adj (unused by reference)
    const float* conv = (const float*)d_in[2];
    const float* Wm   = (const float*)d_in[3];
    float* out     = (float*)d_out;
    float* pos_out = out + (size_t)BDIM * NPTS * OROW;

    const size_t need = (size_t)BDIM * SVOL * CCH * sizeof(float);
    if (ws_size >= need) {
        float* convt = (float*)d_ws;
        transpose_conv<<<dim3(SVOL / 64, BDIM), 256, 0, stream>>>(conv, convt);
        igsc_main<true><<<dim3(NPTS / 64, BDIM), 256, 0, stream>>>(x, convt, Wm, out, pos_out);
    } else {
        igsc_main<false><<<dim3(NPTS / 64, BDIM), 256, 0, stream>>>(x, conv, Wm, out, pos_out);
    }
}